// Round 11
// baseline (1277.502 us; speedup 1.0000x reference)
//
#include <hip/hip_runtime.h>

// Problem constants: B=32, C=1024, N=2048, K=64
#define BB_ 32
#define CC_ 1024
#define NN_ 2048
#define KK_ 64

typedef __bf16 bf16x8 __attribute__((ext_vector_type(8)));
typedef __bf16 bf16x2 __attribute__((ext_vector_type(2)));
typedef float f32x4 __attribute__((ext_vector_type(4)));
typedef unsigned int u32;

__device__ inline unsigned short f2bf_rn(float f) {
    unsigned u = __float_as_uint(f);
    unsigned r = (u + 0x7fffu + ((u >> 16) & 1u)) >> 16;
    return (unsigned short)r;
}

__device__ inline unsigned pack_bf16_rn(float f0, float f1) {
#if __has_builtin(__builtin_amdgcn_cvt_pk_bf16_f32)
    union { bf16x2 v; unsigned u; } x;
    x.v = __builtin_amdgcn_cvt_pk_bf16_f32(f0, f1);
    return x.u;
#else
    return (unsigned)f2bf_rn(f0) | ((unsigned)f2bf_rn(f1) << 16);
#endif
}

__device__ inline void split8(const float* f, uint4* H, uint4* L) {
    union { unsigned u[4]; uint4 v; } hq, lq;
#pragma unroll
    for (int j2 = 0; j2 < 4; j2++) {
        float a = f[2 * j2], c = f[2 * j2 + 1];
        unsigned hp = pack_bf16_rn(a, c);
        float h0f = __uint_as_float((hp & 0xffffu) << 16);
        float h1f = __uint_as_float(hp & 0xffff0000u);
        hq.u[j2] = hp;
        lq.u[j2] = pack_bf16_rn(a - h0f, c - h1f);
    }
    *H = hq.v; *L = lq.v;
}

__device__ inline void gload16(const void* g, void* l) {
    __builtin_amdgcn_global_load_lds(
        (const __attribute__((address_space(1))) u32*)g,
        (__attribute__((address_space(3))) u32*)l, 16, 0, 0);
}

// ---------------------------------------------------------------------------
// convert body: X (fp32) -> Xc split-bf16 swizzled. One "cid" = 256 columns
// of one (lb, kt). Layout per (lb,kt,n): 128 B = 8 chunks of 16 B; chunk for
// term tmr (0=hi,1=lo), k-quad q at position (4*tmr+q) ^ (n&7).
// ---------------------------------------------------------------------------
__device__ void convert_body(const float* __restrict__ X,
                             unsigned char* __restrict__ Xc, int g0,
                             int cid, int t) {
    int chunk = cid & 7;
    int kt = (cid >> 3) & 31;
    int lb = cid >> 8;
    int n = chunk * 256 + t;
    int b = g0 + lb;
    const float* Xb = X + (size_t)b * CC_ * NN_;
    unsigned char* dst = Xc + (((size_t)lb * 32 + kt) * NN_ + n) * 128;
    int sw = n & 7;
#pragma unroll
    for (int q = 0; q < 4; q++) {
        float f[8];
#pragma unroll
        for (int j = 0; j < 8; j++)
            f[j] = Xb[(size_t)(kt * 32 + q * 8 + j) * NN_ + n];
        uint4 hq, lq;
        split8(f, &hq, &lq);
        int p = q ^ sw;
        *(uint4*)(dst + (p << 4)) = hq;
        *(uint4*)(dst + ((p ^ 4) << 4)) = lq;
    }
}

__global__ void convert_kernel(const float* __restrict__ X,
                               unsigned char* __restrict__ Xc, int g0) {
    convert_body(X, Xc, g0, blockIdx.x, threadIdx.x);
}

// ---------------------------------------------------------------------------
// fps block body (256-thread, LDS cross-wave reduce -- the proven version).
// Tie -> lower index (numpy argmax).
// ---------------------------------------------------------------------------
__device__ void fps_block(const float* Gb, int* idx, int b) {
    __shared__ float swv[2][4];
    __shared__ int swi[2][4];
    int t = threadIdx.x;
    float dist[8], nr[8];
#pragma unroll
    for (int r = 0; r < 8; r++) {
        nr[r] = Gb[(size_t)(t + 256 * r) * (NN_ + 1)];
        dist[r] = 1e10f;
    }
    if (t == 0) idx[b * KK_] = 0;
    int far = 0;
    for (int k = 1; k < KK_; k++) {
        float nf = Gb[(size_t)far * (NN_ + 1)];
        const float* grow = Gb + (size_t)far * NN_;
        float v = -1.f;
        int pi = 0;
#pragma unroll
        for (int r = 0; r < 8; r++) {
            float d = nr[r] + nf - 2.f * grow[t + 256 * r];
            dist[r] = fminf(dist[r], d);
            if (dist[r] > v) { v = dist[r]; pi = t + 256 * r; }
        }
#pragma unroll
        for (int off = 32; off; off >>= 1) {
            float ov = __shfl_down(v, off);
            int oi = __shfl_down(pi, off);
            if (ov > v || (ov == v && oi < pi)) { v = ov; pi = oi; }
        }
        int par = k & 1;
        if ((t & 63) == 0) { swv[par][t >> 6] = v; swi[par][t >> 6] = pi; }
        __syncthreads();
        float bv = swv[par][0];
        int bi = swi[par][0];
#pragma unroll
        for (int ww = 1; ww < 4; ww++) {
            float wv2 = swv[par][ww]; int wi2 = swi[par][ww];
            if (wv2 > bv || (wv2 == bv && wi2 < bi)) { bv = wv2; bi = wi2; }
        }
        far = bi;
        if (t == 0) idx[b * KK_ + k] = bi;
    }
}

// ---------------------------------------------------------------------------
// gram (+merged fps +merged convert-of-next-group):
//  blocks [0,nFps)                -> fps on Gprev
//  blocks [nFps, nFps+gs*136)     -> triangular gram tiles (G symmetric!)
//  blocks [nFps+gs*136, +nConv)   -> convert group g+1 into XcNext
// T1 batch<->XCD affinity: gram tile index interleaved so lb = bx % gs.
// BARRIER-FREE k-loop: fragments loaded DIRECTLY global->VGPR (Xc is
// L2-resident; per-lane offsets are kt-invariant). No LDS, no s_barrier in
// the hot loop -> waves run independently; compiler vmcnt-schedules.
// (2-phase LDS staging was latency/rendezvous-bound at 28% MfmaUtil with
// no pipe saturated; occupancy/phase/barrier-count levers all null.)
// Epilogue (unchanged R7): mirror via LDS transpose -> coalesced stores.
// ---------------------------------------------------------------------------
__global__ __launch_bounds__(256, 2) void gram_fps_kernel(
    const unsigned char* __restrict__ Xc, float* __restrict__ G,
    const float* Gprev, int* __restrict__ idx, int nFps, int g0prev,
    const float* __restrict__ X, unsigned char* __restrict__ XcNext,
    int g0next, int nGram, int gs) {
    int bx = (int)blockIdx.x;
    if (bx < nFps) {
        fps_block(Gprev + (size_t)bx * NN_ * NN_, idx, g0prev + bx);
        return;
    }
    bx -= nFps;
    if (bx >= nGram) {
        convert_body(X, XcNext, g0next, bx - nGram, threadIdx.x);
        return;
    }
    // batch<->XCD affinity: interleaved decode (lb fastest-varying)
    int lb = bx % gs;
    int tt = bx / gs;
    int tn = (int)((sqrtf(8.f * tt + 1.f) - 1.f) * 0.5f);
    while ((tn + 1) * (tn + 2) / 2 <= tt) tn++;
    while (tn * (tn + 1) / 2 > tt) tn--;
    int tm = tt - tn * (tn + 1) / 2;      // tm <= tn
    bool diag = (tm == tn);
    int t = threadIdx.x;
    // LDS used ONLY by the epilogue transpose (128 x 132 f32). 2 blocks/CU.
    __shared__ __align__(16) unsigned char sMem[128 * 132 * 4];

    const unsigned char* XcB = Xc + (size_t)lb * 32 * NN_ * 128;
    int w = t >> 6, l = t & 63;
    int m0w = (w & 1) * 64, n0w = (w >> 1) * 64;
    int q = l >> 4, rr = l & 15;

    // per-lane fragment byte offsets within one kt-panel (2048 rows x 128 B);
    // kt only shifts the base by NN_*128 -- offsets are loop-invariant.
    int offA[4], offB[4];
#pragma unroll
    for (int mt = 0; mt < 4; mt++) {
        int ra = m0w + mt * 16 + rr;
        offA[mt] = ra * 128 + ((q ^ (ra & 7)) << 4);
        int rb = n0w + mt * 16 + rr;
        offB[mt] = rb * 128 + ((q ^ (rb & 7)) << 4);
    }
    const unsigned char* Abase = XcB + (size_t)tm * 128 * 128;
    const unsigned char* Bbase = XcB + (size_t)tn * 128 * 128;

    f32x4 zero = {0.f, 0.f, 0.f, 0.f};
    f32x4 acc[4][4];
#pragma unroll
    for (int mt = 0; mt < 4; mt++)
#pragma unroll
        for (int nt = 0; nt < 4; nt++) acc[mt][nt] = zero;

    for (int kt = 0; kt < 32; kt++) {
        const unsigned char* Ak = Abase + (size_t)kt * (NN_ * 128);
        const unsigned char* Bk = Bbase + (size_t)kt * (NN_ * 128);
        bf16x8 ah[4], al[4], bh[4], bl[4];
#pragma unroll
        for (int mt = 0; mt < 4; mt++) {
            ah[mt] = *(const bf16x8*)(Ak + offA[mt]);
            al[mt] = *(const bf16x8*)(Ak + (offA[mt] ^ 64));
            bh[mt] = *(const bf16x8*)(Bk + offB[mt]);
            bl[mt] = *(const bf16x8*)(Bk + (offB[mt] ^ 64));
        }
#pragma unroll
        for (int mt = 0; mt < 4; mt++)
#pragma unroll
            for (int nt = 0; nt < 4; nt++) {
                acc[mt][nt] = __builtin_amdgcn_mfma_f32_16x16x32_bf16(ah[mt], bh[nt], acc[mt][nt], 0, 0, 0);
                acc[mt][nt] = __builtin_amdgcn_mfma_f32_16x16x32_bf16(ah[mt], bl[nt], acc[mt][nt], 0, 0, 0);
                acc[mt][nt] = __builtin_amdgcn_mfma_f32_16x16x32_bf16(al[mt], bh[nt], acc[mt][nt], 0, 0, 0);
            }
    }

    // epilogue: C/D layout col=lane&15, row=(lane>>4)*4+reg.
    // Primary store direct. Mirror via LDS transpose (coalesced float4).
    __syncthreads();
    float* Gb = G + (size_t)lb * NN_ * NN_;
    int i0 = tm * 128, j0 = tn * 128;
    int cc = l & 15;
    float* tb = (float*)sMem;           // 128 x 132 f32
#pragma unroll
    for (int mt = 0; mt < 4; mt++)
#pragma unroll
        for (int nt = 0; nt < 4; nt++)
#pragma unroll
            for (int r = 0; r < 4; r++) {
                int gi = m0w + mt * 16 + q * 4 + r;
                int gj = n0w + nt * 16 + cc;
                float val = acc[mt][nt][r];
                Gb[(size_t)(i0 + gi) * NN_ + j0 + gj] = val;
                if (!diag) tb[gj * 132 + gi] = val;
            }
    if (!diag) {
        __syncthreads();
        // mirror tile: 16384 floats, coalesced float4 stores
#pragma unroll
        for (int m = 0; m < 16; m++) {
            int f = t + 256 * m;
            int jj = f >> 5, sg = f & 31;
            float4 v4 = *(const float4*)(tb + jj * 132 + sg * 4);
            *(float4*)(&Gb[(size_t)(j0 + jj) * NN_ + i0 + sg * 4]) = v4;
        }
    }
}

// ---------------------------------------------------------------------------
// wconv body: W = [w1; wsc] stacked to 256 rows x 2176 -> Wc split-bf16,
// layout [it=68][m=256][128B] (gram format, swizzle by m&7). it = block, m = t.
// ---------------------------------------------------------------------------
__device__ void wconv_body(const float* __restrict__ w1, const float* __restrict__ wsc,
                           unsigned char* __restrict__ Wc, int it, int m) {
    const float* src = (m < 128 ? w1 + (size_t)m * 2176
                                : wsc + (size_t)(m - 128) * 2176) + it * 32;
    unsigned char* dst = Wc + ((size_t)it * 256 + m) * 128;
    int sw = m & 7;
#pragma unroll
    for (int q = 0; q < 4; q++) {
        float f[8];
        *(float4*)f       = *(const float4*)(src + q * 8);
        *(float4*)(f + 4) = *(const float4*)(src + q * 8 + 4);
        uint4 hq, lq;
        split8(f, &hq, &lq);
        int p = q ^ sw;
        *(uint4*)(dst + (p << 4)) = hq;
        *(uint4*)(dst + ((p ^ 4) << 4)) = lq;
    }
}

// ---------------------------------------------------------------------------
// catfillc body: direct split-bf16 emission of cat channels [128,2176) into
// Cc (no fp32 round-trip). One thread: 8 consecutive channels x 1 k.
// ---------------------------------------------------------------------------
__device__ void catfillc_body(const float* __restrict__ X, const float* __restrict__ gf,
                              const int* __restrict__ idx,
                              unsigned char* __restrict__ Cc, int b, int cg, int t) {
    int k = t & 63;
    int chunk = cg * 4 + (t >> 6);          // 0..255
    int ch0 = 128 + chunk * 8;
    float f[8];
    if (ch0 < 1152) {
        int ik = idx[b * KK_ + k];
        const float* Xb = X + ((size_t)b * CC_ + (ch0 - 128)) * NN_ + ik;
#pragma unroll
        for (int j = 0; j < 8; j++) f[j] = Xb[(size_t)j * NN_];
    } else {
        const float* g = gf + (size_t)b * CC_ + (ch0 - 1152);
        *(float4*)f       = *(const float4*)g;
        *(float4*)(f + 4) = *(const float4*)(g + 4);
    }
    uint4 hq, lq;
    split8(f, &hq, &lq);
    int it = ch0 >> 5, q = (ch0 >> 3) & 3;
    unsigned char* dst = Cc + (((size_t)b * 68 + it) * 64 + k) * 128;
    int p = q ^ (k & 7);
    *(uint4*)(dst + (p << 4)) = hq;
    *(uint4*)(dst + ((p ^ 4) << 4)) = lq;
}

// cconv body: cat[b][i][k] fp32 -> Cc split-bf16, it < 4 only (x1 channels).
__device__ void cconv_body(const float* __restrict__ cat,
                           unsigned char* __restrict__ Cc, int it, int b, int t) {
    int k = t & 63, q = t >> 6;
    const float* src = cat + (size_t)b * 2176 * KK_ + (size_t)(it * 32 + q * 8) * KK_ + k;
    float f[8];
#pragma unroll
    for (int j = 0; j < 8; j++) f[j] = src[j * KK_];
    uint4 hq, lq;
    split8(f, &hq, &lq);
    unsigned char* dst = Cc + (((size_t)b * 68 + it) * 64 + k) * 128;
    int p = q ^ (k & 7);
    *(uint4*)(dst + (p << 4)) = hq;
    *(uint4*)(dst + ((p ^ 4) << 4)) = lq;
}

// ---------------------------------------------------------------------------
// x1 (+merged last fps +merged wconv +merged catfillc for ready batches):
//  blocks [0,nFps)          -> fps on Glast (writes idx of last group)
//  next 128                 -> x1: cat[b][o][k] = gf[b]. ps1_w[.][o][k] + b
//  next 68 (if MFMA path)   -> wconv (weights only -- no deps)
//  rest                     -> catfillc for batches [0, BB_-gs) (idx ready)
// ---------------------------------------------------------------------------
__global__ void x1_fps_kernel(const float* __restrict__ gf, const float* __restrict__ w,
                              const float* __restrict__ bias, float* __restrict__ cat,
                              const float* Gprev, int* __restrict__ idx,
                              int g0prev, int nFps, const float* __restrict__ X,
                              const float* __restrict__ w1, const float* __restrict__ wsc,
                              unsigned char* __restrict__ Wc,
                              unsigned char* __restrict__ Cc) {
    int bx = (int)blockIdx.x;
    int t = threadIdx.x;
    if (bx < nFps) {
        fps_block(Gprev + (size_t)bx * NN_ * NN_, idx, g0prev + bx);
        return;
    }
    bx -= nFps;
    if (bx < 128) {
        int okg = bx & 31, bg = bx >> 5;
        int ok = okg * 256 + t;
        int o = ok >> 6, k = ok & 63;
        float acc[8];
#pragma unroll
        for (int j = 0; j < 8; j++) acc[j] = 0.f;
        const float* g = gf + (size_t)(bg * 8) * CC_;
        for (int i = 0; i < CC_; i++) {
            float wv = w[(size_t)(i * 128 + o) * KK_ + k];
#pragma unroll
            for (int j = 0; j < 8; j++) acc[j] += g[j * CC_ + i] * wv;
        }
        float bv = bias[o];
#pragma unroll
        for (int j = 0; j < 8; j++)
            cat[((size_t)(bg * 8 + j) * 2176 + o) * KK_ + k] = acc[j] + bv;
        return;
    }
    bx -= 128;
    if (bx < 68) { wconv_body(w1, wsc, Wc, bx, t); return; }
    bx -= 68;
    catfillc_body(X, gf, idx, Cc, bx >> 6, bx & 63, t);
}

// ---------------------------------------------------------------------------
// tailconv: cconv (needs x1's cat) + catfillc for the last group (needs the
// fps that ran inside x1_fps) [+ wconv/catfillc-all when scratch is in Gbuf].
// ---------------------------------------------------------------------------
__global__ void tailconv_kernel(const float* __restrict__ cat, const float* __restrict__ X,
                                const float* __restrict__ gf, const int* __restrict__ idx,
                                unsigned char* __restrict__ Cc,
                                const float* __restrict__ w1, const float* __restrict__ wsc,
                                unsigned char* __restrict__ Wc, int nW, int catBase) {
    int bx = (int)blockIdx.x;
    int t = threadIdx.x;
    if (bx < 128) { cconv_body(cat, Cc, bx & 3, bx >> 2, t); return; }
    bx -= 128;
    if (bx < nW) { wconv_body(w1, wsc, Wc, bx, t); return; }
    bx -= nW;
    catfillc_body(X, gf, idx, Cc, catBase + (bx >> 6), bx & 63, t);
}

// ---------------------------------------------------------------------------
// mlp1m: P[s][b][256][64] = W[:, s-slice] @ cat[b][s-slice, :], s in [0,8).
// 256 blocks = (b<<3)|s -> s == XCD (blockIdx%8), so each XCD's W slice
// (~288 KB) is L2-resident. Single-barrier double-buffered kt-loop.
// 4-term split-bf16 product (hh+hl+lh+ll) for output-path precision.
// ---------------------------------------------------------------------------
__global__ __launch_bounds__(256, 2) void mlp1m_kernel(
    const unsigned char* __restrict__ Wc, const unsigned char* __restrict__ Cc,
    float* __restrict__ P) {
    int s = blockIdx.x & 7, b = blockIdx.x >> 3;
    int nkt = (s < 4) ? 9 : 8;
    int kt0 = (s < 4) ? s * 9 : 36 + (s - 4) * 8;
    int t = threadIdx.x;
    __shared__ __align__(16) unsigned char sMem[2 * 40960];   // 2 x (A 32K + B 8K)
    int w = t >> 6, l = t & 63;
    int m0w = w * 64;
    int q = l >> 4, rr = l & 15;
    const unsigned char* WcS = Wc + (size_t)kt0 * 32768;
    const unsigned char* CcS = Cc + ((size_t)b * 68 + kt0) * 8192;

    f32x4 zero = {0.f, 0.f, 0.f, 0.f};
    f32x4 acc[4][4];
#pragma unroll
    for (int mt = 0; mt < 4; mt++)
#pragma unroll
        for (int nt = 0; nt < 4; nt++) acc[mt][nt] = zero;

    auto stage = [&](int buf, int kt) {
        const unsigned char* A = WcS + (size_t)kt * 32768;
        const unsigned char* Bc = CcS + (size_t)kt * 8192;
        unsigned char* dA = sMem + buf * 40960;
        unsigned char* dB = dA + 32768;
#pragma unroll
        for (int r = 0; r < 8; r++)
            gload16(A + r * 4096 + t * 16, dA + r * 4096 + t * 16);
#pragma unroll
        for (int r = 0; r < 2; r++)
            gload16(Bc + r * 4096 + t * 16, dB + r * 4096 + t * 16);
    };

    stage(0, 0);
    for (int kt = 0; kt < nkt; kt++) {
        int c = kt & 1;
        asm volatile("s_waitcnt vmcnt(0)" ::: "memory");
        __builtin_amdgcn_sched_barrier(0);
        __builtin_amdgcn_s_barrier();
        __builtin_amdgcn_sched_barrier(0);
        if (kt < nkt - 1) stage(c ^ 1, kt + 1);

        const unsigned char* cA = sMem + c * 40960;
        const unsigned char* cB = cA + 32768;
        bf16x8 ah[4], al[4], bh[4], bl[4];
#pragma unroll
        for (int mt = 0; mt < 4; mt++) {
            int ra = m0w + mt * 16 + rr;
            int pa = q ^ (ra & 7);
            ah[mt] = *(const bf16x8*)(cA + ra * 128 + (pa << 4));
            al[mt] = *(const bf16x8*)(cA + ra * 128 + ((pa ^ 4) << 4));
            int rb = mt * 16 + rr;
            int pb = q ^ (rb & 7);
            bh[mt] = *(const bf16x8*)(cB + rb * 128 + (pb << 4));
            bl[mt] = *(const bf16x8*)(cB + rb * 128 + ((pb ^ 4) << 4));
        }
#pragma unroll
        for (int mt = 0; mt < 4; mt++)
#pragma unroll
            for (int nt = 0; nt < 4; nt++) {
                acc[mt][nt] = __builtin_amdgcn_mfma_f32_16x16x32_bf16(ah[mt], bh[nt], acc[mt][nt], 0, 0, 0);
                acc[mt][nt] = __builtin_amdgcn_mfma_f32_16x16x32_bf16(ah[mt], bl[nt], acc[mt][nt], 0, 0, 0);
                acc[mt][nt] = __builtin_amdgcn_mfma_f32_16x16x32_bf16(al[mt], bh[nt], acc[mt][nt], 0, 0, 0);
                acc[mt][nt] = __builtin_amdgcn_mfma_f32_16x16x32_bf16(al[mt], bl[nt], acc[mt][nt], 0, 0, 0);
            }
    }

    float* Pb = P + (size_t)(s * 32 + b) * 16384;
    int cc = l & 15;
#pragma unroll
    for (int mt = 0; mt < 4; mt++)
#pragma unroll
        for (int nt = 0; nt < 4; nt++)
#pragma unroll
            for (int r = 0; r < 4; r++) {
                int gi = m0w + mt * 16 + q * 4 + r;
                int gj = nt * 16 + cc;
                Pb[(size_t)gi * 64 + gj] = acc[mt][nt][r];
            }
}

// ---------------------------------------------------------------------------
// mlp2p (MFMA path): fuses the 8-slab P reduction (was mred) into mlp2.
// t1 = relu(sum_s P[s][b][o<128] + b1); sc-part folded into acc init.
// k-split x2 for occupancy: 64 blocks, each one batch-k-half.
// ---------------------------------------------------------------------------
__global__ void mlp2p_kernel(const float* __restrict__ P, const float* __restrict__ b1,
                             const float* __restrict__ bsc,
                             const float* __restrict__ w2, const float* __restrict__ b2,
                             const float* __restrict__ w3, const float* __restrict__ b3,
                             const float* __restrict__ w4, const float* __restrict__ b4,
                             float* __restrict__ out) {
    __shared__ float sT[128 * 32];
    __shared__ float sH[128 * 32];
    __shared__ float sR[64 * 32];
    const size_t SLAB = (size_t)32 * 256 * 64;
    int bx = blockIdx.x, t = threadIdx.x;
    int b = bx >> 1, k0 = (bx & 1) * 32;
    const float* Pb = P + (size_t)b * 16384;
    for (int j = t; j < 4096; j += 256) {
        int row = j >> 5, col = j & 31;
        const float* pp = Pb + (size_t)row * 64 + k0 + col;
        float s0 = 0.f;
#pragma unroll
        for (int s = 0; s < 8; s++) s0 += pp[s * SLAB];
        sT[row * 32 + col] = fmaxf(s0 + b1[row], 0.f);
    }
    __syncthreads();
    int k = t & 31, og = t >> 5;            // og in [0,8)

#pragma unroll
    for (int pass = 0; pass < 2; pass++) {
        int o0 = og * 16 + pass * 8;
        float acc[8];
#pragma unroll
        for (int j = 0; j < 8; j++) {
            const float* pp = Pb + (size_t)(128 + o0 + j) * 64 + k0 + k;
            float s0 = 0.f;
#pragma unroll
            for (int s = 0; s < 8; s++) s0 += pp[s * SLAB];
            acc[j] = b2[o0 + j] + bsc[o0 + j] + s0;
        }
        for (int i4 = 0; i4 < 32; i4++) {
            float v0 = sT[(i4 * 4 + 0) * 32 + k];
            float v1 = sT[(i4 * 4 + 1) * 32 + k];
            float v2 = sT[(i4 * 4 + 2) * 32 + k];
            float v3 = sT[(i4 * 4 + 3) * 32 + k];
#pragma unroll
            for (int j = 0; j < 8; j++) {
                float4 wv = *(const float4*)(w2 + (size_t)(o0 + j) * 128 + i4 * 4);
                acc[j] += wv.x * v0 + wv.y * v1 + wv.z * v2 + wv.w * v3;
            }
        }
#pragma unroll
        for (int j = 0; j < 8; j++) sH[(o0 + j) * 32 + k] = acc[j];
    }
    __syncthreads();

    {
        int o0 = og * 8;
        float acc[8];
#pragma unroll
        for (int j = 0; j < 8; j++) acc[j] = b3[o0 + j];
        for (int i4 = 0; i4 < 32; i4++) {
            float v0 = sH[(i4 * 4 + 0) * 32 + k];
            float v1 = sH[(i4 * 4 + 1) * 32 + k];
            float v2 = sH[(i4 * 4 + 2) * 32 + k];
            float v3 = sH[(i4 * 4 + 3) * 32 + k];
#pragma unroll
            for (int j = 0; j < 8; j++) {
                float4 wv = *(const float4*)(w3 + (size_t)(o0 + j) * 128 + i4 * 4);
                acc[j] += wv.x * v0 + wv.y * v1 + wv.z * v2 + wv.w * v3;
            }
        }
#pragma unroll
        for (int j = 0; j < 8; j++) sR[(o0 + j) * 32 + k] = fmaxf(acc[j], 0.f);
    }
    __syncthreads();

    if (t < 96) {
        int o = t % 3;
        int kk = t / 3;                     // 0..31
        float a0 = 0.f, a1 = 0.f, a2 = 0.f, a3 = 0.f;
        for (int i4 = 0; i4 < 16; i4++) {
            float4 wv = *(const float4*)(w4 + o * 64 + i4 * 4);
            a0 += wv.x * sR[(i4 * 4 + 0) * 32 + kk];
            a1 += wv.y * sR[(i4 * 4 + 1) * 32 + kk];
            a2 += wv.z * sR[(i4 * 4 + 2) * 32 + kk];
            a3 += wv.w * sR[(i4 * 4 + 3) * 32 + kk];
        }
        out[((size_t)b * KK_ + k0 + kk) * 3 + o] = b4[o] + ((a0 + a1) + (a2 + a3));
    }
}

// ---------------------------------------------------------------------------
// fp32 fallback path (workspace too small for the MFMA-mlp1 scratch)
// ---------------------------------------------------------------------------
__global__ void catfill_kernel(const float* __restrict__ X, const float* __restrict__ gf,
                               const int* __restrict__ idx, float* __restrict__ cat) {
    int b = blockIdx.y;
    int t = threadIdx.x;
    int ch = 128 + blockIdx.x * 4 + (t >> 6);
    int k = t & 63;
    float v;
    if (ch < 1152) {
        int c = ch - 128;
        int ik = idx[b * KK_ + k];
        v = X[((size_t)b * CC_ + c) * NN_ + ik];
    } else {
        v = gf[b * CC_ + (ch - 1152)];
    }
    cat[((size_t)b * 2176 + ch) * KK_ + k] = v;
}

__global__ void mlp1_kernel(const float* __restrict__ cat, const float* __restrict__ w1,
                            const float* __restrict__ b1, const float* __restrict__ wsc,
                            const float* __restrict__ bsc, float* __restrict__ t1,
                            float* __restrict__ sc) {
    __shared__ float red[2][16][64];
    int b = blockIdx.y, og = blockIdx.x;
    int t = threadIdx.x;
    int k = t & 63, sub = t >> 6;
    int o0 = og * 4;
    const float* cb = cat + (size_t)b * 2176 * KK_;
    float a1[4], a2[4];
#pragma unroll
    for (int j = 0; j < 4; j++) { a1[j] = 0.f; a2[j] = 0.f; }
    int iBeg = sub * 544;
    int off = (b & 7) * 68;
#pragma unroll 1
    for (int seg = 0; seg < 2; seg++) {
        int s0 = iBeg + (seg ? 0 : off);
        int s1 = seg ? iBeg + off : iBeg + 544;
        for (int i = s0; i < s1; i += 4) {
            float v0 = cb[(i + 0) * KK_ + k];
            float v1 = cb[(i + 1) * KK_ + k];
            float v2 = cb[(i + 2) * KK_ + k];
            float v3 = cb[(i + 3) * KK_ + k];
#pragma unroll
            for (int j = 0; j < 4; j++) {
                float4 wv = *(const float4*)(w1 + (size_t)(o0 + j) * 2176 + i);
                a1[j] += wv.x * v0 + wv.y * v1 + wv.z * v2 + wv.w * v3;
                float4 ws = *(const float4*)(wsc + (size_t)(o0 + j) * 2176 + i);
                a2[j] += ws.x * v0 + ws.y * v1 + ws.z * v2 + ws.w * v3;
            }
        }
    }
#pragma unroll
    for (int j = 0; j < 4; j++) {
        red[0][sub * 4 + j][k] = a1[j];
        red[1][sub * 4 + j][k] = a2[j];
    }
    __syncthreads();
#pragma unroll
    for (int p = t; p < 512; p += 256) {
        int m = p >> 8;
        int j = (p >> 6) & 3;
        int kk = p & 63;
        float s = red[m][j][kk] + red[m][4 + j][kk] + red[m][8 + j][kk] + red[m][12 + j][kk];
        int o = o0 + j;
        size_t oidx = ((size_t)b * 128 + o) * KK_ + kk;
        if (m == 0) t1[oidx] = fmaxf(s + b1[o], 0.f);
        else        sc[oidx] = s + bsc[o];
    }
}

__global__ void mlp2_kernel(const float* __restrict__ t1, const float* __restrict__ sc,
                            const float* __restrict__ w2, const float* __restrict__ b2,
                            const float* __restrict__ w3, const float* __restrict__ b3,
                            const float* __restrict__ w4, const float* __restrict__ b4,
                            float* __restrict__ out) {
    __shared__ float sT[128 * 32];
    __shared__ float sH[128 * 32];
    __shared__ float sR[64 * 32];
    int bx = blockIdx.x, t = threadIdx.x;
    int b = bx >> 1, k0 = (bx & 1) * 32;
    for (int j = t; j < 1024; j += 256) {
        int row = j >> 3, c4 = (j & 7) * 4;
        *(float4*)(sT + row * 32 + c4) =
            *(const float4*)(t1 + (size_t)b * 8192 + row * 64 + k0 + c4);
    }
    __syncthreads();
    int k = t & 31, og = t >> 5;
    const float* scb = sc + (size_t)b * 8192;

#pragma unroll
    for (int pass = 0; pass < 2; pass++) {
        int o0 = og * 16 + pass * 8;
        float acc[8];
#pragma unroll
        for (int j = 0; j < 8; j++) acc[j] = b2[o0 + j] + scb[(o0 + j) * 64 + k0 + k];
        for (int i4 = 0; i4 < 32; i4++) {
            float v0 = sT[(i4 * 4 + 0) * 32 + k];
            float v1 = sT[(i4 * 4 + 1) * 32 + k];
            float v2 = sT[(i4 * 4 + 2) * 32 + k];
            float v3 = sT[(i4 * 4 + 3) * 32 + k];
#pragma unroll
            for (int j = 0; j < 8; j++) {
                float4 wv = *(const float4*)(w2 + (size_t)(o0 + j) * 128 + i4 * 4);
                acc[j] += wv.x * v0 + wv.y * v1 + wv.z * v2 + wv.w * v3;
            }
        }
#pragma unroll
        for (int j = 0; j < 8; j++) sH[(o0 + j) * 32 + k] = acc[j];
    }
    __syncthreads();

    {
        int o0 = og * 8;
        float acc[8];
#pragma unroll
        for (int j = 0; j < 8; j++) acc[j] = b3[o0 + j];
        for (int i4 = 0; i4 < 32; i4++) {
            float v0 = sH[(i4 * 4 + 0) * 32 + k];
            float v1 = sH[(i4 * 4 + 1) * 32 + k];
            float v2 = sH[(i4 * 4 + 2) * 32 + k];
            float v3 = sH[(i4 * 4 + 3) * 32 + k];
#pragma unroll
            for (int j = 0; j < 8; j++) {
                float4 wv = *(const float4*)(w3 + (size_t)(o0 + j) * 128 + i4 * 4);
                acc[j] += wv.x * v0 + wv.y * v1 + wv.z * v2 + wv.w * v3;
            }
        }
#pragma unroll
        for (int j = 0; j < 8; j++) sR[(o0 + j) * 32 + k] = fmaxf(acc[j], 0.f);
    }
    __syncthreads();

    if (t < 96) {
        int o = t % 3;
        int kk = t / 3;
        float a0 = 0.f, a1 = 0.f, a2 = 0.f, a3 = 0.f;
        for (int i4 = 0; i4 < 16; i4++) {
            float4 wv = *(const float4*)(w4 + o * 64 + i4 * 4);
            a0 += wv.x * sR[(i4 * 4 + 0) * 32 + kk];
            a1 += wv.y * sR[(i4 * 4 + 1) * 32 + kk];
            a2 += wv.z * sR[(i4 * 4 + 2) * 32 + kk];
            a3 += wv.w * sR[(i4 * 4 + 3) * 32 + kk];
        }
        out[((size_t)b * KK_ + k0 + kk) * 3 + o] = b4[o] + ((a0 + a1) + (a2 + a3));
    }
}

// ---------------------------------------------------------------------------
extern "C" void kernel_launch(void* const* d_in, const int* in_sizes, int n_in,
                              void* d_out, int out_size, void* d_ws, size_t ws_size,
                              hipStream_t stream) {
    const float* X    = (const float*)d_in[0];
    const float* gf   = (const float*)d_in[1];
    const float* ps1w = (const float*)d_in[2];
    const float* ps1b = (const float*)d_in[3];
    const float* w1   = (const float*)d_in[4];
    const float* b1   = (const float*)d_in[5];
    const float* w2   = (const float*)d_in[6];
    const float* b2   = (const float*)d_in[7];
    const float* wsc  = (const float*)d_in[8];
    const float* bscp = (const float*)d_in[9];
    const float* w3   = (const float*)d_in[10];
    const float* b3   = (const float*)d_in[11];
    const float* w4   = (const float*)d_in[12];
    const float* b4   = (const float*)d_in[13];
    float* out = (float*)d_out;

    const size_t G_PER  = (size_t)NN_ * NN_ * 4;         // 16 MB / batch
    const size_t XC_PER = (size_t)32 * NN_ * 128;        // 8 MB / batch
    const size_t IDX_B  = (size_t)BB_ * KK_ * 4;
    const size_t CAT_B  = (size_t)BB_ * 2176 * KK_ * 4;  // 17.8 MB
    const size_t T1_B   = (size_t)BB_ * 128 * KK_ * 4;   // 1 MB
    size_t rest = IDX_B + CAT_B + 2 * T1_B;

    // ws ladder: gs=8 top rung (gs=16 regressed: 2 batches/XCD broke the
    // per-XCD L2 residency, HBM traffic ~2x).
    int gs = 1, merged = 0, pipe = 0;
    {
        const int tg[8]  = {8, 8, 4, 4, 2, 2, 1, 1};
        const int tmg[8] = {1, 1, 1, 1, 1, 1, 1, 0};
        const int tp[8]  = {1, 0, 1, 0, 1, 0, 0, 0};
        for (int i = 0; i < 8; i++) {
            size_t need = (size_t)(tmg[i] ? 2 : 1) * tg[i] * G_PER
                        + (size_t)(tp[i] ? 2 : 1) * tg[i] * XC_PER + rest;
            if (ws_size >= need) { gs = tg[i]; merged = tmg[i]; pipe = tp[i]; break; }
        }
    }

    char* ws = (char*)d_ws;
    float* Gbuf = (float*)ws;
    size_t gBufBytes = (size_t)(merged ? 2 : 1) * gs * G_PER;
    unsigned char* Xc0 = (unsigned char*)(ws + gBufBytes);
    unsigned char* Xc1 = Xc0 + (pipe ? (size_t)gs * XC_PER : 0);
    size_t xcBytes = (size_t)(pipe ? 2 : 1) * gs * XC_PER;
    char* p = (char*)Xc0 + xcBytes;
    int* idxws = (int*)p;    p += IDX_B;
    float* cat = (float*)p;  p += CAT_B;
    float* t1  = (float*)p;  p += T1_B;
    float* sc  = (float*)p;

    // MFMA-mlp1 scratch: Xc region (dead after last gram) or Gbuf region.
    const size_t WC_B = (size_t)68 * 256 * 128;          // 2.23 MB
    const size_t CC_B = (size_t)BB_ * 68 * 64 * 128;     // 17.8 MB
    const size_t P_B  = (size_t)8 * BB_ * 256 * 64 * 4;  // 16.8 MB
    char* scratch = nullptr;
    int inXc = 0;
    if (xcBytes >= WC_B + CC_B + P_B) { scratch = (char*)Xc0; inXc = 1; }
    else if (gBufBytes >= WC_B + CC_B + P_B) scratch = (char*)Gbuf;
    unsigned char* Wc = scratch ? (unsigned char*)scratch : nullptr;
    unsigned char* Cc = scratch ? Wc + WC_B : nullptr;
    float* P = scratch ? (float*)(Cc + CC_B) : nullptr;

    int ng = BB_ / gs;
    size_t halfElems = (size_t)gs * NN_ * NN_;
    int nGram = gs * 136;
    int nConvAll = 256 * gs;

    if (pipe) convert_kernel<<<nConvAll, 256, 0, stream>>>(X, Xc0, 0);
    for (int g = 0; g < ng; g++) {
        int g0 = g * gs;
        unsigned char* Xcur  = (g & 1) ? Xc1 : Xc0;
        unsigned char* Xnext = (g & 1) ? Xc0 : Xc1;
        if (!pipe) {
            Xcur = Xc0;
            convert_kernel<<<nConvAll, 256, 0, stream>>>(X, Xc0, g0);
        }
        float* Gcur = Gbuf + (merged ? (size_t)(g & 1) * halfElems : 0);
        float* Gprev = Gbuf + (merged ? (size_t)((g & 1) ^ 1) * halfElems : 0);
        int nFps = (merged && g > 0) ? gs : 0;
        int nConv = (pipe && g < ng - 1) ? nConvAll : 0;
        gram_fps_kernel<<<nFps + nGram + nConv, 256, 0, stream>>>(
            Xcur, Gcur, Gprev, idxws, nFps, g0 - gs, X, Xnext, g0 + gs, nGram, gs);
        if (!merged) {
            gram_fps_kernel<<<gs, 256, 0, stream>>>(
                Xcur, Gcur, Gcur, idxws, gs, g0, X, Xnext, 0, 0, gs);
        }
    }
    int nFpsLast = merged ? gs : 0;
    float* Glast = Gbuf + (merged ? (size_t)((ng - 1) & 1) * halfElems : 0);
    int nExtra = (scratch && inXc) ? 68 + (BB_ - gs) * 64 : 0;
    x1_fps_kernel<<<nFpsLast + 128 + nExtra, 256, 0, stream>>>(
        gf, ps1w, ps1b, cat, Glast, idxws, BB_ - gs, nFpsLast,
        X, w1, wsc, Wc, Cc);
    if (scratch) {
        int nW = inXc ? 0 : 68;
        int catBase = inXc ? BB_ - gs : 0;
        int nCat = inXc ? gs : BB_;
        tailconv_kernel<<<128 + nW + nCat * 64, 256, 0, stream>>>(
            cat, X, gf, idxws, Cc, w1, wsc, Wc, nW, catBase);
        mlp1m_kernel<<<256, 256, 0, stream>>>(Wc, Cc, P);
        mlp2p_kernel<<<BB_ * 2, 256, 0, stream>>>(P, b1, bscp, w2, b2, w3, b3, w4, b4, out);
    } else {
        catfill_kernel<<<dim3(512, BB_), 256, 0, stream>>>(X, gf, idxws, cat);
        mlp1_kernel<<<dim3(32, BB_), 256, 0, stream>>>(cat, w1, b1, wsc, bscp, t1, sc);
        mlp2_kernel<<<BB_ * 2, 256, 0, stream>>>(t1, sc, w2, b2, w3, b3, w4, b4, out);
    }
}

// Round 12
// 1123.377 us; speedup vs baseline: 1.1372x; 1.1372x over previous
//
#include <hip/hip_runtime.h>

// Problem constants: B=32, C=1024, N=2048, K=64
#define BB_ 32
#define CC_ 1024
#define NN_ 2048
#define KK_ 64

typedef __bf16 bf16x8 __attribute__((ext_vector_type(8)));
typedef __bf16 bf16x2 __attribute__((ext_vector_type(2)));
typedef float f32x4 __attribute__((ext_vector_type(4)));
typedef unsigned int u32;

__device__ inline unsigned short f2bf_rn(float f) {
    unsigned u = __float_as_uint(f);
    unsigned r = (u + 0x7fffu + ((u >> 16) & 1u)) >> 16;
    return (unsigned short)r;
}

__device__ inline unsigned pack_bf16_rn(float f0, float f1) {
#if __has_builtin(__builtin_amdgcn_cvt_pk_bf16_f32)
    union { bf16x2 v; unsigned u; } x;
    x.v = __builtin_amdgcn_cvt_pk_bf16_f32(f0, f1);
    return x.u;
#else
    return (unsigned)f2bf_rn(f0) | ((unsigned)f2bf_rn(f1) << 16);
#endif
}

__device__ inline void split8(const float* f, uint4* H, uint4* L) {
    union { unsigned u[4]; uint4 v; } hq, lq;
#pragma unroll
    for (int j2 = 0; j2 < 4; j2++) {
        float a = f[2 * j2], c = f[2 * j2 + 1];
        unsigned hp = pack_bf16_rn(a, c);
        float h0f = __uint_as_float((hp & 0xffffu) << 16);
        float h1f = __uint_as_float(hp & 0xffff0000u);
        hq.u[j2] = hp;
        lq.u[j2] = pack_bf16_rn(a - h0f, c - h1f);
    }
    *H = hq.v; *L = lq.v;
}

__device__ inline void gload16(const void* g, void* l) {
    __builtin_amdgcn_global_load_lds(
        (const __attribute__((address_space(1))) u32*)g,
        (__attribute__((address_space(3))) u32*)l, 16, 0, 0);
}

// ---------------------------------------------------------------------------
// convert body: X (fp32) -> Xc split-bf16 swizzled. One "cid" = 256 columns
// of one (lb, kt). Layout per (lb,kt,n): 128 B = 8 chunks of 16 B; chunk for
// term tmr (0=hi,1=lo), k-quad q at position (4*tmr+q) ^ (n&7).
// ---------------------------------------------------------------------------
__device__ void convert_body(const float* __restrict__ X,
                             unsigned char* __restrict__ Xc, int g0,
                             int cid, int t) {
    int chunk = cid & 7;
    int kt = (cid >> 3) & 31;
    int lb = cid >> 8;
    int n = chunk * 256 + t;
    int b = g0 + lb;
    const float* Xb = X + (size_t)b * CC_ * NN_;
    unsigned char* dst = Xc + (((size_t)lb * 32 + kt) * NN_ + n) * 128;
    int sw = n & 7;
#pragma unroll
    for (int q = 0; q < 4; q++) {
        float f[8];
#pragma unroll
        for (int j = 0; j < 8; j++)
            f[j] = Xb[(size_t)(kt * 32 + q * 8 + j) * NN_ + n];
        uint4 hq, lq;
        split8(f, &hq, &lq);
        int p = q ^ sw;
        *(uint4*)(dst + (p << 4)) = hq;
        *(uint4*)(dst + ((p ^ 4) << 4)) = lq;
    }
}

__global__ void convert_kernel(const float* __restrict__ X,
                               unsigned char* __restrict__ Xc, int g0) {
    convert_body(X, Xc, g0, blockIdx.x, threadIdx.x);
}

// ---------------------------------------------------------------------------
// fps block body (256-thread, LDS cross-wave reduce -- the proven version).
// Tie -> lower index (numpy argmax).
// ---------------------------------------------------------------------------
__device__ void fps_block(const float* Gb, int* idx, int b) {
    __shared__ float swv[2][4];
    __shared__ int swi[2][4];
    int t = threadIdx.x;
    float dist[8], nr[8];
#pragma unroll
    for (int r = 0; r < 8; r++) {
        nr[r] = Gb[(size_t)(t + 256 * r) * (NN_ + 1)];
        dist[r] = 1e10f;
    }
    if (t == 0) idx[b * KK_] = 0;
    int far = 0;
    for (int k = 1; k < KK_; k++) {
        float nf = Gb[(size_t)far * (NN_ + 1)];
        const float* grow = Gb + (size_t)far * NN_;
        float v = -1.f;
        int pi = 0;
#pragma unroll
        for (int r = 0; r < 8; r++) {
            float d = nr[r] + nf - 2.f * grow[t + 256 * r];
            dist[r] = fminf(dist[r], d);
            if (dist[r] > v) { v = dist[r]; pi = t + 256 * r; }
        }
#pragma unroll
        for (int off = 32; off; off >>= 1) {
            float ov = __shfl_down(v, off);
            int oi = __shfl_down(pi, off);
            if (ov > v || (ov == v && oi < pi)) { v = ov; pi = oi; }
        }
        int par = k & 1;
        if ((t & 63) == 0) { swv[par][t >> 6] = v; swi[par][t >> 6] = pi; }
        __syncthreads();
        float bv = swv[par][0];
        int bi = swi[par][0];
#pragma unroll
        for (int ww = 1; ww < 4; ww++) {
            float wv2 = swv[par][ww]; int wi2 = swi[par][ww];
            if (wv2 > bv || (wv2 == bv && wi2 < bi)) { bv = wv2; bi = wi2; }
        }
        far = bi;
        if (t == 0) idx[b * KK_ + k] = bi;
    }
}

// ---------------------------------------------------------------------------
// gram (+merged fps +merged convert-of-next-group):
//  blocks [0,nFps)                -> fps on Gprev
//  blocks [nFps, nFps+gs*136)     -> triangular gram tiles (G symmetric!)
//  blocks [nFps+gs*136, +nConv)   -> convert group g+1 into XcNext
// T1 batch<->XCD affinity: gram tile index interleaved so lb = bx % gs.
// Single-barrier double-buffered kt-loop (verified best: 161us/dispatch).
// Falsified alternatives: 4-phase (-18%), 8-wave (-5%), gs=16 (-15%),
// barrier-free direct-global (-28%), 3 blocks/CU (0), 2-barrier (0).
// Epilogue: explicit __syncthreads then mirror via LDS transpose.
// ---------------------------------------------------------------------------
__global__ __launch_bounds__(256, 2) void gram_fps_kernel(
    const unsigned char* __restrict__ Xc, float* __restrict__ G,
    const float* Gprev, int* __restrict__ idx, int nFps, int g0prev,
    const float* __restrict__ X, unsigned char* __restrict__ XcNext,
    int g0next, int nGram, int gs) {
    int bx = (int)blockIdx.x;
    if (bx < nFps) {
        fps_block(Gprev + (size_t)bx * NN_ * NN_, idx, g0prev + bx);
        return;
    }
    bx -= nFps;
    if (bx >= nGram) {
        convert_body(X, XcNext, g0next, bx - nGram, threadIdx.x);
        return;
    }
    // batch<->XCD affinity: interleaved decode (lb fastest-varying)
    int lb = bx % gs;
    int tt = bx / gs;
    int tn = (int)((sqrtf(8.f * tt + 1.f) - 1.f) * 0.5f);
    while ((tn + 1) * (tn + 2) / 2 <= tt) tn++;
    while (tn * (tn + 1) / 2 > tt) tn--;
    int tm = tt - tn * (tn + 1) / 2;      // tm <= tn
    bool diag = (tm == tn);
    int t = threadIdx.x;
    // 2 x (sA 16K + sB 16K) double buffer = 64 KB; epilogue reuses it as a
    // 128x132 f32 transpose buffer (67584 B). 2 blocks/CU.
    __shared__ __align__(16) unsigned char sMem[128 * 132 * 4];

    const unsigned char* XcB = Xc + (size_t)lb * 32 * NN_ * 128;
    int w = t >> 6, l = t & 63;
    int m0w = (w & 1) * 64, n0w = (w >> 1) * 64;
    int q = l >> 4, rr = l & 15;

    f32x4 zero = {0.f, 0.f, 0.f, 0.f};
    f32x4 acc[4][4];
#pragma unroll
    for (int mt = 0; mt < 4; mt++)
#pragma unroll
        for (int nt = 0; nt < 4; nt++) acc[mt][nt] = zero;

    // uniform staging (diag stages B too -> uniform vm counts)
    auto stage = [&](int buf, int kt) {
        const unsigned char* Ab = XcB + ((size_t)kt * NN_ + (size_t)tm * 128) * 128;
        const unsigned char* Bb = XcB + ((size_t)kt * NN_ + (size_t)tn * 128) * 128;
        unsigned char* dA = sMem + buf * 32768;
        unsigned char* dB = dA + 16384;
#pragma unroll
        for (int r = 0; r < 4; r++) {
            gload16(Ab + r * 4096 + t * 16, dA + r * 4096 + t * 16);
            gload16(Bb + r * 4096 + t * 16, dB + r * 4096 + t * 16);
        }
    };

    stage(0, 0);
    for (int kt = 0; kt < 32; kt++) {
        int c = kt & 1;
        asm volatile("s_waitcnt vmcnt(0)" ::: "memory");   // own stage(kt) done
        __builtin_amdgcn_sched_barrier(0);
        __builtin_amdgcn_s_barrier();    // all waves staged + prev reads done
        __builtin_amdgcn_sched_barrier(0);
        if (kt < 31) stage(c ^ 1, kt + 1);   // issue next tile (hidden)

        const unsigned char* cA = sMem + c * 32768;
        const unsigned char* cB = cA + 16384;
        bf16x8 ah[4], al[4], bh[4], bl[4];
#pragma unroll
        for (int mt = 0; mt < 4; mt++) {
            int ra = m0w + mt * 16 + rr;
            int pa = q ^ (ra & 7);
            ah[mt] = *(const bf16x8*)(cA + ra * 128 + (pa << 4));
            al[mt] = *(const bf16x8*)(cA + ra * 128 + ((pa ^ 4) << 4));
            int rb = n0w + mt * 16 + rr;
            int pb = q ^ (rb & 7);
            bh[mt] = *(const bf16x8*)(cB + rb * 128 + (pb << 4));
            bl[mt] = *(const bf16x8*)(cB + rb * 128 + ((pb ^ 4) << 4));
        }
#pragma unroll
        for (int mt = 0; mt < 4; mt++)
#pragma unroll
            for (int nt = 0; nt < 4; nt++) {
                acc[mt][nt] = __builtin_amdgcn_mfma_f32_16x16x32_bf16(ah[mt], bh[nt], acc[mt][nt], 0, 0, 0);
                acc[mt][nt] = __builtin_amdgcn_mfma_f32_16x16x32_bf16(ah[mt], bl[nt], acc[mt][nt], 0, 0, 0);
                acc[mt][nt] = __builtin_amdgcn_mfma_f32_16x16x32_bf16(al[mt], bh[nt], acc[mt][nt], 0, 0, 0);
            }
    }

    // epilogue: C/D layout col=lane&15, row=(lane>>4)*4+reg.
    // Barrier first: laggards may still be reading the last buffer.
    __syncthreads();
    float* Gb = G + (size_t)lb * NN_ * NN_;
    int i0 = tm * 128, j0 = tn * 128;
    int cc = l & 15;
    float* tb = (float*)sMem;           // 128 x 132 f32
#pragma unroll
    for (int mt = 0; mt < 4; mt++)
#pragma unroll
        for (int nt = 0; nt < 4; nt++)
#pragma unroll
            for (int r = 0; r < 4; r++) {
                int gi = m0w + mt * 16 + q * 4 + r;
                int gj = n0w + nt * 16 + cc;
                float val = acc[mt][nt][r];
                Gb[(size_t)(i0 + gi) * NN_ + j0 + gj] = val;
                if (!diag) tb[gj * 132 + gi] = val;
            }
    if (!diag) {
        __syncthreads();
        // mirror tile: 16384 floats, coalesced float4 stores
#pragma unroll
        for (int m = 0; m < 16; m++) {
            int f = t + 256 * m;
            int jj = f >> 5, sg = f & 31;
            float4 v4 = *(const float4*)(tb + jj * 132 + sg * 4);
            *(float4*)(&Gb[(size_t)(j0 + jj) * NN_ + i0 + sg * 4]) = v4;
        }
    }
}

// ---------------------------------------------------------------------------
// wconv body: W = [w1; wsc] stacked to 256 rows x 2176 -> Wc split-bf16,
// layout [it=68][m=256][128B] (gram format, swizzle by m&7). it = block, m = t.
// ---------------------------------------------------------------------------
__device__ void wconv_body(const float* __restrict__ w1, const float* __restrict__ wsc,
                           unsigned char* __restrict__ Wc, int it, int m) {
    const float* src = (m < 128 ? w1 + (size_t)m * 2176
                                : wsc + (size_t)(m - 128) * 2176) + it * 32;
    unsigned char* dst = Wc + ((size_t)it * 256 + m) * 128;
    int sw = m & 7;
#pragma unroll
    for (int q = 0; q < 4; q++) {
        float f[8];
        *(float4*)f       = *(const float4*)(src + q * 8);
        *(float4*)(f + 4) = *(const float4*)(src + q * 8 + 4);
        uint4 hq, lq;
        split8(f, &hq, &lq);
        int p = q ^ sw;
        *(uint4*)(dst + (p << 4)) = hq;
        *(uint4*)(dst + ((p ^ 4) << 4)) = lq;
    }
}

// ---------------------------------------------------------------------------
// catfillc body: direct split-bf16 emission of cat channels [128,2176) into
// Cc (no fp32 round-trip). One thread: 8 consecutive channels x 1 k.
// ---------------------------------------------------------------------------
__device__ void catfillc_body(const float* __restrict__ X, const float* __restrict__ gf,
                              const int* __restrict__ idx,
                              unsigned char* __restrict__ Cc, int b, int cg, int t) {
    int k = t & 63;
    int chunk = cg * 4 + (t >> 6);          // 0..255
    int ch0 = 128 + chunk * 8;
    float f[8];
    if (ch0 < 1152) {
        int ik = idx[b * KK_ + k];
        const float* Xb = X + ((size_t)b * CC_ + (ch0 - 128)) * NN_ + ik;
#pragma unroll
        for (int j = 0; j < 8; j++) f[j] = Xb[(size_t)j * NN_];
    } else {
        const float* g = gf + (size_t)b * CC_ + (ch0 - 1152);
        *(float4*)f       = *(const float4*)g;
        *(float4*)(f + 4) = *(const float4*)(g + 4);
    }
    uint4 hq, lq;
    split8(f, &hq, &lq);
    int it = ch0 >> 5, q = (ch0 >> 3) & 3;
    unsigned char* dst = Cc + (((size_t)b * 68 + it) * 64 + k) * 128;
    int p = q ^ (k & 7);
    *(uint4*)(dst + (p << 4)) = hq;
    *(uint4*)(dst + ((p ^ 4) << 4)) = lq;
}

// cconv body: cat[b][i][k] fp32 -> Cc split-bf16, it < 4 only (x1 channels).
__device__ void cconv_body(const float* __restrict__ cat,
                           unsigned char* __restrict__ Cc, int it, int b, int t) {
    int k = t & 63, q = t >> 6;
    const float* src = cat + (size_t)b * 2176 * KK_ + (size_t)(it * 32 + q * 8) * KK_ + k;
    float f[8];
#pragma unroll
    for (int j = 0; j < 8; j++) f[j] = src[j * KK_];
    uint4 hq, lq;
    split8(f, &hq, &lq);
    unsigned char* dst = Cc + (((size_t)b * 68 + it) * 64 + k) * 128;
    int p = q ^ (k & 7);
    *(uint4*)(dst + (p << 4)) = hq;
    *(uint4*)(dst + ((p ^ 4) << 4)) = lq;
}

// ---------------------------------------------------------------------------
// x1 (+merged last fps +merged wconv +merged catfillc for ready batches):
//  blocks [0,nFps)          -> fps on Glast (writes idx of last group)
//  next 128                 -> x1: cat[b][o][k] = gf[b]. ps1_w[.][o][k] + b
//  next 68 (if MFMA path)   -> wconv (weights only -- no deps)
//  rest                     -> catfillc for batches [0, BB_-gs) (idx ready)
// ---------------------------------------------------------------------------
__global__ void x1_fps_kernel(const float* __restrict__ gf, const float* __restrict__ w,
                              const float* __restrict__ bias, float* __restrict__ cat,
                              const float* Gprev, int* __restrict__ idx,
                              int g0prev, int nFps, const float* __restrict__ X,
                              const float* __restrict__ w1, const float* __restrict__ wsc,
                              unsigned char* __restrict__ Wc,
                              unsigned char* __restrict__ Cc) {
    int bx = (int)blockIdx.x;
    int t = threadIdx.x;
    if (bx < nFps) {
        fps_block(Gprev + (size_t)bx * NN_ * NN_, idx, g0prev + bx);
        return;
    }
    bx -= nFps;
    if (bx < 128) {
        int okg = bx & 31, bg = bx >> 5;
        int ok = okg * 256 + t;
        int o = ok >> 6, k = ok & 63;
        float acc[8];
#pragma unroll
        for (int j = 0; j < 8; j++) acc[j] = 0.f;
        const float* g = gf + (size_t)(bg * 8) * CC_;
        for (int i = 0; i < CC_; i++) {
            float wv = w[(size_t)(i * 128 + o) * KK_ + k];
#pragma unroll
            for (int j = 0; j < 8; j++) acc[j] += g[j * CC_ + i] * wv;
        }
        float bv = bias[o];
#pragma unroll
        for (int j = 0; j < 8; j++)
            cat[((size_t)(bg * 8 + j) * 2176 + o) * KK_ + k] = acc[j] + bv;
        return;
    }
    bx -= 128;
    if (bx < 68) { wconv_body(w1, wsc, Wc, bx, t); return; }
    bx -= 68;
    catfillc_body(X, gf, idx, Cc, bx >> 6, bx & 63, t);
}

// ---------------------------------------------------------------------------
// tailconv: cconv (needs x1's cat) + catfillc for the last group (needs the
// fps that ran inside x1_fps) [+ wconv/catfillc-all when scratch is in Gbuf].
// ---------------------------------------------------------------------------
__global__ void tailconv_kernel(const float* __restrict__ cat, const float* __restrict__ X,
                                const float* __restrict__ gf, const int* __restrict__ idx,
                                unsigned char* __restrict__ Cc,
                                const float* __restrict__ w1, const float* __restrict__ wsc,
                                unsigned char* __restrict__ Wc, int nW, int catBase) {
    int bx = (int)blockIdx.x;
    int t = threadIdx.x;
    if (bx < 128) { cconv_body(cat, Cc, bx & 3, bx >> 2, t); return; }
    bx -= 128;
    if (bx < nW) { wconv_body(w1, wsc, Wc, bx, t); return; }
    bx -= nW;
    catfillc_body(X, gf, idx, Cc, catBase + (bx >> 6), bx & 63, t);
}

// ---------------------------------------------------------------------------
// mlp1m: P[s][b][256][64] = W[:, s-slice] @ cat[b][s-slice, :], s in [0,8).
// 256 blocks = (b<<3)|s -> s == XCD (blockIdx%8), so each XCD's W slice
// (~288 KB) is L2-resident. Single-barrier double-buffered kt-loop.
// 4-term split-bf16 product (hh+hl+lh+ll) for output-path precision.
// ---------------------------------------------------------------------------
__global__ __launch_bounds__(256, 2) void mlp1m_kernel(
    const unsigned char* __restrict__ Wc, const unsigned char* __restrict__ Cc,
    float* __restrict__ P) {
    int s = blockIdx.x & 7, b = blockIdx.x >> 3;
    int nkt = (s < 4) ? 9 : 8;
    int kt0 = (s < 4) ? s * 9 : 36 + (s - 4) * 8;
    int t = threadIdx.x;
    __shared__ __align__(16) unsigned char sMem[2 * 40960];   // 2 x (A 32K + B 8K)
    int w = t >> 6, l = t & 63;
    int m0w = w * 64;
    int q = l >> 4, rr = l & 15;
    const unsigned char* WcS = Wc + (size_t)kt0 * 32768;
    const unsigned char* CcS = Cc + ((size_t)b * 68 + kt0) * 8192;

    f32x4 zero = {0.f, 0.f, 0.f, 0.f};
    f32x4 acc[4][4];
#pragma unroll
    for (int mt = 0; mt < 4; mt++)
#pragma unroll
        for (int nt = 0; nt < 4; nt++) acc[mt][nt] = zero;

    auto stage = [&](int buf, int kt) {
        const unsigned char* A = WcS + (size_t)kt * 32768;
        const unsigned char* Bc = CcS + (size_t)kt * 8192;
        unsigned char* dA = sMem + buf * 40960;
        unsigned char* dB = dA + 32768;
#pragma unroll
        for (int r = 0; r < 8; r++)
            gload16(A + r * 4096 + t * 16, dA + r * 4096 + t * 16);
#pragma unroll
        for (int r = 0; r < 2; r++)
            gload16(Bc + r * 4096 + t * 16, dB + r * 4096 + t * 16);
    };

    stage(0, 0);
    for (int kt = 0; kt < nkt; kt++) {
        int c = kt & 1;
        asm volatile("s_waitcnt vmcnt(0)" ::: "memory");
        __builtin_amdgcn_sched_barrier(0);
        __builtin_amdgcn_s_barrier();
        __builtin_amdgcn_sched_barrier(0);
        if (kt < nkt - 1) stage(c ^ 1, kt + 1);

        const unsigned char* cA = sMem + c * 40960;
        const unsigned char* cB = cA + 32768;
        bf16x8 ah[4], al[4], bh[4], bl[4];
#pragma unroll
        for (int mt = 0; mt < 4; mt++) {
            int ra = m0w + mt * 16 + rr;
            int pa = q ^ (ra & 7);
            ah[mt] = *(const bf16x8*)(cA + ra * 128 + (pa << 4));
            al[mt] = *(const bf16x8*)(cA + ra * 128 + ((pa ^ 4) << 4));
            int rb = mt * 16 + rr;
            int pb = q ^ (rb & 7);
            bh[mt] = *(const bf16x8*)(cB + rb * 128 + (pb << 4));
            bl[mt] = *(const bf16x8*)(cB + rb * 128 + ((pb ^ 4) << 4));
        }
#pragma unroll
        for (int mt = 0; mt < 4; mt++)
#pragma unroll
            for (int nt = 0; nt < 4; nt++) {
                acc[mt][nt] = __builtin_amdgcn_mfma_f32_16x16x32_bf16(ah[mt], bh[nt], acc[mt][nt], 0, 0, 0);
                acc[mt][nt] = __builtin_amdgcn_mfma_f32_16x16x32_bf16(ah[mt], bl[nt], acc[mt][nt], 0, 0, 0);
                acc[mt][nt] = __builtin_amdgcn_mfma_f32_16x16x32_bf16(al[mt], bh[nt], acc[mt][nt], 0, 0, 0);
                acc[mt][nt] = __builtin_amdgcn_mfma_f32_16x16x32_bf16(al[mt], bl[nt], acc[mt][nt], 0, 0, 0);
            }
    }

    float* Pb = P + (size_t)(s * 32 + b) * 16384;
    int cc = l & 15;
#pragma unroll
    for (int mt = 0; mt < 4; mt++)
#pragma unroll
        for (int nt = 0; nt < 4; nt++)
#pragma unroll
            for (int r = 0; r < 4; r++) {
                int gi = m0w + mt * 16 + q * 4 + r;
                int gj = nt * 16 + cc;
                Pb[(size_t)gi * 64 + gj] = acc[mt][nt][r];
            }
}

// ---------------------------------------------------------------------------
// mlp2p (MFMA path): fuses the 8-slab P reduction (was mred) into mlp2.
// t1 = relu(sum_s P[s][b][o<128] + b1); sc-part folded into acc init.
// k-split x2 for occupancy: 64 blocks, each one batch-k-half.
// ---------------------------------------------------------------------------
__global__ void mlp2p_kernel(const float* __restrict__ P, const float* __restrict__ b1,
                             const float* __restrict__ bsc,
                             const float* __restrict__ w2, const float* __restrict__ b2,
                             const float* __restrict__ w3, const float* __restrict__ b3,
                             const float* __restrict__ w4, const float* __restrict__ b4,
                             float* __restrict__ out) {
    __shared__ float sT[128 * 32];
    __shared__ float sH[128 * 32];
    __shared__ float sR[64 * 32];
    const size_t SLAB = (size_t)32 * 256 * 64;
    int bx = blockIdx.x, t = threadIdx.x;
    int b = bx >> 1, k0 = (bx & 1) * 32;
    const float* Pb = P + (size_t)b * 16384;
    for (int j = t; j < 4096; j += 256) {
        int row = j >> 5, col = j & 31;
        const float* pp = Pb + (size_t)row * 64 + k0 + col;
        float s0 = 0.f;
#pragma unroll
        for (int s = 0; s < 8; s++) s0 += pp[s * SLAB];
        sT[row * 32 + col] = fmaxf(s0 + b1[row], 0.f);
    }
    __syncthreads();
    int k = t & 31, og = t >> 5;            // og in [0,8)

#pragma unroll
    for (int pass = 0; pass < 2; pass++) {
        int o0 = og * 16 + pass * 8;
        float acc[8];
#pragma unroll
        for (int j = 0; j < 8; j++) {
            const float* pp = Pb + (size_t)(128 + o0 + j) * 64 + k0 + k;
            float s0 = 0.f;
#pragma unroll
            for (int s = 0; s < 8; s++) s0 += pp[s * SLAB];
            acc[j] = b2[o0 + j] + bsc[o0 + j] + s0;
        }
        for (int i4 = 0; i4 < 32; i4++) {
            float v0 = sT[(i4 * 4 + 0) * 32 + k];
            float v1 = sT[(i4 * 4 + 1) * 32 + k];
            float v2 = sT[(i4 * 4 + 2) * 32 + k];
            float v3 = sT[(i4 * 4 + 3) * 32 + k];
#pragma unroll
            for (int j = 0; j < 8; j++) {
                float4 wv = *(const float4*)(w2 + (size_t)(o0 + j) * 128 + i4 * 4);
                acc[j] += wv.x * v0 + wv.y * v1 + wv.z * v2 + wv.w * v3;
            }
        }
#pragma unroll
        for (int j = 0; j < 8; j++) sH[(o0 + j) * 32 + k] = acc[j];
    }
    __syncthreads();

    {
        int o0 = og * 8;
        float acc[8];
#pragma unroll
        for (int j = 0; j < 8; j++) acc[j] = b3[o0 + j];
        for (int i4 = 0; i4 < 32; i4++) {
            float v0 = sH[(i4 * 4 + 0) * 32 + k];
            float v1 = sH[(i4 * 4 + 1) * 32 + k];
            float v2 = sH[(i4 * 4 + 2) * 32 + k];
            float v3 = sH[(i4 * 4 + 3) * 32 + k];
#pragma unroll
            for (int j = 0; j < 8; j++) {
                float4 wv = *(const float4*)(w3 + (size_t)(o0 + j) * 128 + i4 * 4);
                acc[j] += wv.x * v0 + wv.y * v1 + wv.z * v2 + wv.w * v3;
            }
        }
#pragma unroll
        for (int j = 0; j < 8; j++) sR[(o0 + j) * 32 + k] = fmaxf(acc[j], 0.f);
    }
    __syncthreads();

    if (t < 96) {
        int o = t % 3;
        int kk = t / 3;                     // 0..31
        float a0 = 0.f, a1 = 0.f, a2 = 0.f, a3 = 0.f;
        for (int i4 = 0; i4 < 16; i4++) {
            float4 wv = *(const float4*)(w4 + o * 64 + i4 * 4);
            a0 += wv.x * sR[(i4 * 4 + 0) * 32 + kk];
            a1 += wv.y * sR[(i4 * 4 + 1) * 32 + kk];
            a2 += wv.z * sR[(i4 * 4 + 2) * 32 + kk];
            a3 += wv.w * sR[(i4 * 4 + 3) * 32 + kk];
        }
        out[((size_t)b * KK_ + k0 + kk) * 3 + o] = b4[o] + ((a0 + a1) + (a2 + a3));
    }
}

// ---------------------------------------------------------------------------
// fp32 fallback path (workspace too small for the MFMA-mlp1 scratch)
// ---------------------------------------------------------------------------
__global__ void catfill_kernel(const float* __restrict__ X, const float* __restrict__ gf,
                               const int* __restrict__ idx, float* __restrict__ cat) {
    int b = blockIdx.y;
    int t = threadIdx.x;
    int ch = 128 + blockIdx.x * 4 + (t >> 6);
    int k = t & 63;
    float v;
    if (ch < 1152) {
        int c = ch - 128;
        int ik = idx[b * KK_ + k];
        v = X[((size_t)b * CC_ + c) * NN_ + ik];
    } else {
        v = gf[b * CC_ + (ch - 1152)];
    }
    cat[((size_t)b * 2176 + ch) * KK_ + k] = v;
}

__global__ void mlp1_kernel(const float* __restrict__ cat, const float* __restrict__ w1,
                            const float* __restrict__ b1, const float* __restrict__ wsc,
                            const float* __restrict__ bsc, float* __restrict__ t1,
                            float* __restrict__ sc) {
    __shared__ float red[2][16][64];
    int b = blockIdx.y, og = blockIdx.x;
    int t = threadIdx.x;
    int k = t & 63, sub = t >> 6;
    int o0 = og * 4;
    const float* cb = cat + (size_t)b * 2176 * KK_;
    float a1[4], a2[4];
#pragma unroll
    for (int j = 0; j < 4; j++) { a1[j] = 0.f; a2[j] = 0.f; }
    int iBeg = sub * 544;
    int off = (b & 7) * 68;
#pragma unroll 1
    for (int seg = 0; seg < 2; seg++) {
        int s0 = iBeg + (seg ? 0 : off);
        int s1 = seg ? iBeg + off : iBeg + 544;
        for (int i = s0; i < s1; i += 4) {
            float v0 = cb[(i + 0) * KK_ + k];
            float v1 = cb[(i + 1) * KK_ + k];
            float v2 = cb[(i + 2) * KK_ + k];
            float v3 = cb[(i + 3) * KK_ + k];
#pragma unroll
            for (int j = 0; j < 4; j++) {
                float4 wv = *(const float4*)(w1 + (size_t)(o0 + j) * 2176 + i);
                a1[j] += wv.x * v0 + wv.y * v1 + wv.z * v2 + wv.w * v3;
                float4 ws = *(const float4*)(wsc + (size_t)(o0 + j) * 2176 + i);
                a2[j] += ws.x * v0 + ws.y * v1 + ws.z * v2 + ws.w * v3;
            }
        }
    }
#pragma unroll
    for (int j = 0; j < 4; j++) {
        red[0][sub * 4 + j][k] = a1[j];
        red[1][sub * 4 + j][k] = a2[j];
    }
    __syncthreads();
#pragma unroll
    for (int p = t; p < 512; p += 256) {
        int m = p >> 8;
        int j = (p >> 6) & 3;
        int kk = p & 63;
        float s = red[m][j][kk] + red[m][4 + j][kk] + red[m][8 + j][kk] + red[m][12 + j][kk];
        int o = o0 + j;
        size_t oidx = ((size_t)b * 128 + o) * KK_ + kk;
        if (m == 0) t1[oidx] = fmaxf(s + b1[o], 0.f);
        else        sc[oidx] = s + bsc[o];
    }
}

__global__ void mlp2_kernel(const float* __restrict__ t1, const float* __restrict__ sc,
                            const float* __restrict__ w2, const float* __restrict__ b2,
                            const float* __restrict__ w3, const float* __restrict__ b3,
                            const float* __restrict__ w4, const float* __restrict__ b4,
                            float* __restrict__ out) {
    __shared__ float sT[128 * 32];
    __shared__ float sH[128 * 32];
    __shared__ float sR[64 * 32];
    int bx = blockIdx.x, t = threadIdx.x;
    int b = bx >> 1, k0 = (bx & 1) * 32;
    for (int j = t; j < 1024; j += 256) {
        int row = j >> 3, c4 = (j & 7) * 4;
        *(float4*)(sT + row * 32 + c4) =
            *(const float4*)(t1 + (size_t)b * 8192 + row * 64 + k0 + c4);
    }
    __syncthreads();
    int k = t & 31, og = t >> 5;
    const float* scb = sc + (size_t)b * 8192;

#pragma unroll
    for (int pass = 0; pass < 2; pass++) {
        int o0 = og * 16 + pass * 8;
        float acc[8];
#pragma unroll
        for (int j = 0; j < 8; j++) acc[j] = b2[o0 + j] + scb[(o0 + j) * 64 + k0 + k];
        for (int i4 = 0; i4 < 32; i4++) {
            float v0 = sT[(i4 * 4 + 0) * 32 + k];
            float v1 = sT[(i4 * 4 + 1) * 32 + k];
            float v2 = sT[(i4 * 4 + 2) * 32 + k];
            float v3 = sT[(i4 * 4 + 3) * 32 + k];
#pragma unroll
            for (int j = 0; j < 8; j++) {
                float4 wv = *(const float4*)(w2 + (size_t)(o0 + j) * 128 + i4 * 4);
                acc[j] += wv.x * v0 + wv.y * v1 + wv.z * v2 + wv.w * v3;
            }
        }
#pragma unroll
        for (int j = 0; j < 8; j++) sH[(o0 + j) * 32 + k] = acc[j];
    }
    __syncthreads();

    {
        int o0 = og * 8;
        float acc[8];
#pragma unroll
        for (int j = 0; j < 8; j++) acc[j] = b3[o0 + j];
        for (int i4 = 0; i4 < 32; i4++) {
            float v0 = sH[(i4 * 4 + 0) * 32 + k];
            float v1 = sH[(i4 * 4 + 1) * 32 + k];
            float v2 = sH[(i4 * 4 + 2) * 32 + k];
            float v3 = sH[(i4 * 4 + 3) * 32 + k];
#pragma unroll
            for (int j = 0; j < 8; j++) {
                float4 wv = *(const float4*)(w3 + (size_t)(o0 + j) * 128 + i4 * 4);
                acc[j] += wv.x * v0 + wv.y * v1 + wv.z * v2 + wv.w * v3;
            }
        }
#pragma unroll
        for (int j = 0; j < 8; j++) sR[(o0 + j) * 32 + k] = fmaxf(acc[j], 0.f);
    }
    __syncthreads();

    if (t < 96) {
        int o = t % 3;
        int kk = t / 3;
        float a0 = 0.f, a1 = 0.f, a2 = 0.f, a3 = 0.f;
        for (int i4 = 0; i4 < 16; i4++) {
            float4 wv = *(const float4*)(w4 + o * 64 + i4 * 4);
            a0 += wv.x * sR[(i4 * 4 + 0) * 32 + kk];
            a1 += wv.y * sR[(i4 * 4 + 1) * 32 + kk];
            a2 += wv.z * sR[(i4 * 4 + 2) * 32 + kk];
            a3 += wv.w * sR[(i4 * 4 + 3) * 32 + kk];
        }
        out[((size_t)b * KK_ + k0 + kk) * 3 + o] = b4[o] + ((a0 + a1) + (a2 + a3));
    }
}

// ---------------------------------------------------------------------------
extern "C" void kernel_launch(void* const* d_in, const int* in_sizes, int n_in,
                              void* d_out, int out_size, void* d_ws, size_t ws_size,
                              hipStream_t stream) {
    const float* X    = (const float*)d_in[0];
    const float* gf   = (const float*)d_in[1];
    const float* ps1w = (const float*)d_in[2];
    const float* ps1b = (const float*)d_in[3];
    const float* w1   = (const float*)d_in[4];
    const float* b1   = (const float*)d_in[5];
    const float* w2   = (const float*)d_in[6];
    const float* b2   = (const float*)d_in[7];
    const float* wsc  = (const float*)d_in[8];
    const float* bscp = (const float*)d_in[9];
    const float* w3   = (const float*)d_in[10];
    const float* b3   = (const float*)d_in[11];
    const float* w4   = (const float*)d_in[12];
    const float* b4   = (const float*)d_in[13];
    float* out = (float*)d_out;

    const size_t G_PER  = (size_t)NN_ * NN_ * 4;         // 16 MB / batch
    const size_t XC_PER = (size_t)32 * NN_ * 128;        // 8 MB / batch
    const size_t IDX_B  = (size_t)BB_ * KK_ * 4;
    const size_t CAT_B  = (size_t)BB_ * 2176 * KK_ * 4;  // 17.8 MB
    const size_t T1_B   = (size_t)BB_ * 128 * KK_ * 4;   // 1 MB
    size_t rest = IDX_B + CAT_B + 2 * T1_B;

    // ws ladder: gs=8 top rung (gs=16 regressed: 2 batches/XCD broke the
    // per-XCD L2 residency, HBM traffic ~2x).
    int gs = 1, merged = 0, pipe = 0;
    {
        const int tg[8]  = {8, 8, 4, 4, 2, 2, 1, 1};
        const int tmg[8] = {1, 1, 1, 1, 1, 1, 1, 0};
        const int tp[8]  = {1, 0, 1, 0, 1, 0, 0, 0};
        for (int i = 0; i < 8; i++) {
            size_t need = (size_t)(tmg[i] ? 2 : 1) * tg[i] * G_PER
                        + (size_t)(tp[i] ? 2 : 1) * tg[i] * XC_PER + rest;
            if (ws_size >= need) { gs = tg[i]; merged = tmg[i]; pipe = tp[i]; break; }
        }
    }

    char* ws = (char*)d_ws;
    float* Gbuf = (float*)ws;
    size_t gBufBytes = (size_t)(merged ? 2 : 1) * gs * G_PER;
    unsigned char* Xc0 = (unsigned char*)(ws + gBufBytes);
    unsigned char* Xc1 = Xc0 + (pipe ? (size_t)gs * XC_PER : 0);
    size_t xcBytes = (size_t)(pipe ? 2 : 1) * gs * XC_PER;
    char* p = (char*)Xc0 + xcBytes;
    int* idxws = (int*)p;    p += IDX_B;
    float* cat = (float*)p;  p += CAT_B;
    float* t1  = (float*)p;  p += T1_B;
    float* sc  = (float*)p;

    // MFMA-mlp1 scratch: Xc region (dead after last gram) or Gbuf region.
    const size_t WC_B = (size_t)68 * 256 * 128;          // 2.23 MB
    const size_t CC_B = (size_t)BB_ * 68 * 64 * 128;     // 17.8 MB
    const size_t P_B  = (size_t)8 * BB_ * 256 * 64 * 4;  // 16.8 MB
    char* scratch = nullptr;
    int inXc = 0;
    if (xcBytes >= WC_B + CC_B + P_B) { scratch = (char*)Xc0; inXc = 1; }
    else if (gBufBytes >= WC_B + CC_B + P_B) scratch = (char*)Gbuf;
    unsigned char* Wc = scratch ? (unsigned char*)scratch : nullptr;
    unsigned char* Cc = scratch ? Wc + WC_B : nullptr;
    float* P = scratch ? (float*)(Cc + CC_B) : nullptr;

    int ng = BB_ / gs;
    size_t halfElems = (size_t)gs * NN_ * NN_;
    int nGram = gs * 136;
    int nConvAll = 256 * gs;

    if (pipe) convert_kernel<<<nConvAll, 256, 0, stream>>>(X, Xc0, 0);
    for (int g = 0; g < ng; g++) {
        int g0 = g * gs;
        unsigned char* Xcur  = (g & 1) ? Xc1 : Xc0;
        unsigned char* Xnext = (g & 1) ? Xc0 : Xc1;
        if (!pipe) {
            Xcur = Xc0;
            convert_kernel<<<nConvAll, 256, 0, stream>>>(X, Xc0, g0);
        }
        float* Gcur = Gbuf + (merged ? (size_t)(g & 1) * halfElems : 0);
        float* Gprev = Gbuf + (merged ? (size_t)((g & 1) ^ 1) * halfElems : 0);
        int nFps = (merged && g > 0) ? gs : 0;
        int nConv = (pipe && g < ng - 1) ? nConvAll : 0;
        gram_fps_kernel<<<nFps + nGram + nConv, 256, 0, stream>>>(
            Xcur, Gcur, Gprev, idxws, nFps, g0 - gs, X, Xnext, g0 + gs, nGram, gs);
        if (!merged) {
            gram_fps_kernel<<<gs, 256, 0, stream>>>(
                Xcur, Gcur, Gcur, idxws, gs, g0, X, Xnext, 0, 0, gs);
        }
    }
    int nFpsLast = merged ? gs : 0;
    float* Glast = Gbuf + (merged ? (size_t)((ng - 1) & 1) * halfElems : 0);
    int nExtra = (scratch && inXc) ? 68 + (BB_ - gs) * 64 : 0;
    x1_fps_kernel<<<nFpsLast + 128 + nExtra, 256, 0, stream>>>(
        gf, ps1w, ps1b, cat, Glast, idxws, BB_ - gs, nFpsLast,
        X, w1, wsc, Wc, Cc);
    if (scratch) {
        int nW = inXc ? 0 : 68;
        int catBase = inXc ? BB_ - gs : 0;
        int nCat = inXc ? gs : BB_;
        tailconv_kernel<<<128 + nW + nCat * 64, 256, 0, stream>>>(
            cat, X, gf, idxws, Cc, w1, wsc, Wc, nW, catBase);
        mlp1m_kernel<<<256, 256, 0, stream>>>(Wc, Cc, P);
        mlp2p_kernel<<<BB_ * 2, 256, 0, stream>>>(P, b1, bscp, w2, b2, w3, b3, w4, b4, out);
    } else {
        catfill_kernel<<<dim3(512, BB_), 256, 0, stream>>>(X, gf, idxws, cat);
        mlp1_kernel<<<dim3(32, BB_), 256, 0, stream>>>(cat, w1, b1, wsc, bscp, t1, sc);
        mlp2_kernel<<<BB_ * 2, 256, 0, stream>>>(t1, sc, w2, b2, w3, b3, w4, b4, out);
    }
}